// Round 14
// baseline (93.263 us; speedup 1.0000x reference)
//
#include <hip/hip_runtime.h>
#include <hip/hip_bf16.h>
#include <stdint.h>

#define S_LEN 4096
#define HID   1024
#define NH    16
#define HD    64
#define HWIN  128

typedef __bf16 bf16x8 __attribute__((ext_vector_type(8)));
typedef float  f32x4  __attribute__((ext_vector_type(4)));
typedef unsigned short u16x8 __attribute__((ext_vector_type(8)));

typedef const __attribute__((address_space(1))) unsigned int* gas_ptr;
typedef __attribute__((address_space(3))) unsigned int* las_ptr;

__device__ __forceinline__ float bf2f(unsigned short u) {
  union { float f; uint32_t i; } w; w.i = ((uint32_t)u) << 16; return w.f;
}
__device__ __forceinline__ unsigned short f2bf(float f) {
  union { float f; uint32_t i; } w; w.f = f;
  uint32_t r = (w.i + 0x7FFFu + ((w.i >> 16) & 1u)) >> 16;
  return (unsigned short)r;
}

__device__ __forceinline__ void gld_lds16(const void* g, void* l) {
  __builtin_amdgcn_global_load_lds((gas_ptr)g, (las_ptr)l, 16, 0, 0);
}

// ---------------------------------------------------------------- convert (grid-stride)
__global__ __launch_bounds__(256) void convert_all(
    const float* __restrict__ x,
    const float* __restrict__ wq, const float* __restrict__ wk,
    const float* __restrict__ wv, const float* __restrict__ wo,
    unsigned short* __restrict__ xb,
    unsigned short* __restrict__ wqb, unsigned short* __restrict__ wkb,
    unsigned short* __restrict__ wvb, unsigned short* __restrict__ wob) {
  const int XF4 = (S_LEN * HID) / 4;      // 1048576
  const int WF4 = (HID * HID) / 4;        // 262144
  int i = blockIdx.x * 256 + threadIdx.x; // grid 2048 blocks -> 524288 threads
#pragma unroll
  for (int it = 0; it < 4; it++, i += 524288) {
    const float* in; unsigned short* out; int off;
    if (i < XF4) { in = x; out = xb; off = i; }
    else {
      int j = i - XF4;
      int w = j >> 18;
      off = j & (WF4 - 1);
      switch (w) {
        case 0:  in = wq; out = wqb; break;
        case 1:  in = wk; out = wkb; break;
        case 2:  in = wv; out = wvb; break;
        default: in = wo; out = wob; break;
      }
    }
    float4 v = reinterpret_cast<const float4*>(in)[off];
    ushort4 o;
    o.x = f2bf(v.x); o.y = f2bf(v.y); o.z = f2bf(v.z); o.w = f2bf(v.w);
    reinterpret_cast<ushort4*>(out)[off] = o;
  }
}

// ---------------------------------------------------------------- QKV GEMM: BM=128, BN=64
// Grid (32,16,3) = 1536 blocks = 6/CU. 4 waves as 2M x 2N, per-wave 64x32 out.
// BK=64 single-buffer, XOR-swizzled LDS (preswizzled source + same-XOR reads).
// mode 0: bf16 C[r*HID+c]; mode 1: bf16 C[c*S_LEN+r] via LDS-transpose epilogue.
__global__ __launch_bounds__(256, 2) void gemm_qkv(
    const unsigned short* __restrict__ xb,
    const unsigned short* __restrict__ wqb, const unsigned short* __restrict__ wkb,
    const unsigned short* __restrict__ wvb,
    unsigned short* __restrict__ Qb, unsigned short* __restrict__ Kb,
    unsigned short* __restrict__ Vt) {
  __shared__ __align__(16) unsigned short SM[128 * 64 + 64 * 64];  // 24 KB
  unsigned short* As = SM;             // 128x64
  unsigned short* Bs = SM + 128 * 64;  // 64x64
  const unsigned short* B = (blockIdx.z == 0) ? wqb : (blockIdx.z == 1) ? wkb : wvb;
  unsigned short* Cb      = (blockIdx.z == 0) ? Qb  : (blockIdx.z == 1) ? Kb  : Vt;
  const int mode = (blockIdx.z == 2) ? 1 : 0;
  constexpr int K = HID;
  const int tid  = threadIdx.x;
  const int lane = tid & 63;
  const int wave = tid >> 6;
  const int wm = wave >> 1, wn = wave & 1;
  const int m0 = blockIdx.x * 128;
  const int n0 = blockIdx.y * 64;
  const int cl = lane & 15, g = lane >> 4;

  f32x4 acc[4][2];
#pragma unroll
  for (int i = 0; i < 4; i++)
#pragma unroll
    for (int j = 0; j < 2; j++) acc[i][j] = f32x4{0.f, 0.f, 0.f, 0.f};

  const unsigned short* Ap[4];
  const unsigned short* Bp[2];
  int ldsoA[4], ldsoB[2];
#pragma unroll
  for (int u = 0; u < 4; u++) {
    int s = tid + u * 256;
    int row = s >> 3, c16 = s & 7;
    Ap[u] = xb + (size_t)(m0 + row) * K + ((c16 ^ (row & 7)) << 3);
    ldsoA[u] = s * 8;
  }
#pragma unroll
  for (int u = 0; u < 2; u++) {
    int s = tid + u * 256;
    int row = s >> 3, c16 = s & 7;
    Bp[u] = B + (size_t)(n0 + row) * K + ((c16 ^ (row & 7)) << 3);
    ldsoB[u] = s * 8;
  }

  for (int k0 = 0; k0 < K; k0 += 64) {
#pragma unroll
    for (int u = 0; u < 4; u++) gld_lds16(Ap[u] + k0, &As[ldsoA[u]]);
#pragma unroll
    for (int u = 0; u < 2; u++) gld_lds16(Bp[u] + k0, &Bs[ldsoB[u]]);
    __syncthreads();
#pragma unroll
    for (int kk = 0; kk < 2; kk++) {
      bf16x8 a[4], b[2];
#pragma unroll
      for (int mi = 0; mi < 4; mi++) {
        int row = wm * 64 + mi * 16 + cl;
        int c16 = (kk * 4 + g) ^ (row & 7);
        a[mi] = *reinterpret_cast<const bf16x8*>(&As[row * 64 + c16 * 8]);
      }
#pragma unroll
      for (int ni = 0; ni < 2; ni++) {
        int row = wn * 32 + ni * 16 + cl;
        int c16 = (kk * 4 + g) ^ (row & 7);
        b[ni] = *reinterpret_cast<const bf16x8*>(&Bs[row * 64 + c16 * 8]);
      }
#pragma unroll
      for (int mi = 0; mi < 4; mi++)
#pragma unroll
        for (int ni = 0; ni < 2; ni++)
          acc[mi][ni] = __builtin_amdgcn_mfma_f32_16x16x32_bf16(a[mi], b[ni], acc[mi][ni], 0, 0, 0);
    }
    __syncthreads();
  }

  const int rl = g * 4;
  if (mode == 1) {
    // epilogue LDS transpose: T(c,r), c in [0,64), r in [0,128); 16 KB in As region
#pragma unroll
    for (int mi = 0; mi < 4; mi++)
#pragma unroll
      for (int ni = 0; ni < 2; ni++) {
        int c = wn * 32 + ni * 16 + cl;
        int slot = (wm * 16 + mi * 4 + g) ^ ((c & 7) << 2);
        uint2 u;
        u.x = (uint32_t)f2bf(acc[mi][ni][0]) | ((uint32_t)f2bf(acc[mi][ni][1]) << 16);
        u.y = (uint32_t)f2bf(acc[mi][ni][2]) | ((uint32_t)f2bf(acc[mi][ni][3]) << 16);
        *reinterpret_cast<uint2*>(&SM[c * 128 + slot * 4]) = u;
      }
    __syncthreads();
    const int rgrp = tid & 15;
#pragma unroll
    for (int p = 0; p < 4; p++) {
      int c = p * 16 + (tid >> 4);
      int sa = (2 * rgrp) ^ ((c & 7) << 2);
      int sb = (2 * rgrp + 1) ^ ((c & 7) << 2);
      uint2 a2 = *reinterpret_cast<const uint2*>(&SM[c * 128 + sa * 4]);
      uint2 b2 = *reinterpret_cast<const uint2*>(&SM[c * 128 + sb * 4]);
      uint4 o{a2.x, a2.y, b2.x, b2.y};
      *reinterpret_cast<uint4*>(&Cb[(size_t)(n0 + c) * S_LEN + m0 + rgrp * 8]) = o;
    }
    return;
  }
#pragma unroll
  for (int mi = 0; mi < 4; mi++)
#pragma unroll
    for (int ni = 0; ni < 2; ni++)
#pragma unroll
      for (int i = 0; i < 4; i++) {
        int r = m0 + wm * 64 + mi * 16 + rl + i;
        int c = n0 + wn * 32 + ni * 16 + cl;
        Cb[(size_t)r * HID + c] = f2bf(acc[mi][ni][i]);
      }
}

// ---------------------------------------------------------------- proj GEMM: BM=128, BN=64 (R13 known-good)
__global__ __launch_bounds__(256, 2) void gemm_proj(
    unsigned short* __restrict__ Ob, const unsigned short* __restrict__ wob,
    const float* __restrict__ mw, const float* __restrict__ lw,
    const float* __restrict__ ow, float* __restrict__ out) {
  if (blockIdx.x == 0) {
    const float LOG2E = 1.44269504f;
    for (int cc = threadIdx.x; cc < HID; cc += 256) {
      int h = cc >> 6, d = cc & 63;
      float m_g = -1e30f;
#pragma unroll
      for (int c = 0; c < 16; c++) m_g = fmaxf(m_g, mw[h * 16 + c]);
      float lsum = 0.f, osum = 0.f;
#pragma unroll
      for (int c = 0; c < 16; c++) {
        float w = exp2f((mw[h * 16 + c] - m_g) * LOG2E);
        lsum += lw[h * 16 + c] * w;
        osum += ow[(size_t)(h * 16 + c) * HD + d] * w;
      }
      Ob[cc] = f2bf(osum / lsum);
    }
    asm volatile("s_waitcnt vmcnt(0)" ::: "memory");
    __syncthreads();
  }

  __shared__ __align__(16) unsigned short As[128 * 64];  // 16 KB
  __shared__ __align__(16) unsigned short Bs[64 * 64];   // 8 KB
  constexpr int K = HID;
  const int tid  = threadIdx.x;
  const int lane = tid & 63;
  const int wave = tid >> 6;
  const int wm = wave >> 1, wn = wave & 1;
  const int m0 = blockIdx.x * 128;
  const int n0 = blockIdx.y * 64;
  const int cl = lane & 15, g = lane >> 4;

  f32x4 acc[4][2];
#pragma unroll
  for (int i = 0; i < 4; i++)
#pragma unroll
    for (int j = 0; j < 2; j++) acc[i][j] = f32x4{0.f, 0.f, 0.f, 0.f};

  const unsigned short* Ap[4];
  const unsigned short* Bp[2];
  int ldsoA[4], ldsoB[2];
#pragma unroll
  for (int u = 0; u < 4; u++) {
    int s = tid + u * 256;
    int row = s >> 3, c16 = s & 7;
    Ap[u] = Ob + (size_t)(m0 + row) * K + ((c16 ^ (row & 7)) << 3);
    ldsoA[u] = s * 8;
  }
#pragma unroll
  for (int u = 0; u < 2; u++) {
    int s = tid + u * 256;
    int row = s >> 3, c16 = s & 7;
    Bp[u] = wob + (size_t)(n0 + row) * K + ((c16 ^ (row & 7)) << 3);
    ldsoB[u] = s * 8;
  }

  for (int k0 = 0; k0 < K; k0 += 64) {
#pragma unroll
    for (int u = 0; u < 4; u++) gld_lds16(Ap[u] + k0, &As[ldsoA[u]]);
#pragma unroll
    for (int u = 0; u < 2; u++) gld_lds16(Bp[u] + k0, &Bs[ldsoB[u]]);
    __syncthreads();
#pragma unroll
    for (int kk = 0; kk < 2; kk++) {
      bf16x8 a[4], b[2];
#pragma unroll
      for (int mi = 0; mi < 4; mi++) {
        int row = wm * 64 + mi * 16 + cl;
        int c16 = (kk * 4 + g) ^ (row & 7);
        a[mi] = *reinterpret_cast<const bf16x8*>(&As[row * 64 + c16 * 8]);
      }
#pragma unroll
      for (int ni = 0; ni < 2; ni++) {
        int row = wn * 32 + ni * 16 + cl;
        int c16 = (kk * 4 + g) ^ (row & 7);
        b[ni] = *reinterpret_cast<const bf16x8*>(&Bs[row * 64 + c16 * 8]);
      }
#pragma unroll
      for (int mi = 0; mi < 4; mi++)
#pragma unroll
        for (int ni = 0; ni < 2; ni++)
          acc[mi][ni] = __builtin_amdgcn_mfma_f32_16x16x32_bf16(a[mi], b[ni], acc[mi][ni], 0, 0, 0);
    }
    __syncthreads();
  }

  const int rl = g * 4;
#pragma unroll
  for (int mi = 0; mi < 4; mi++)
#pragma unroll
    for (int ni = 0; ni < 2; ni++)
#pragma unroll
      for (int i = 0; i < 4; i++) {
        int r = m0 + wm * 64 + mi * 16 + rl + i;
        int c = n0 + wn * 32 + ni * 16 + cl;
        out[(size_t)r * HID + c] = acc[mi][ni][i];
      }
}

// ---------------------------------------------------------------- windowed attention (+ fused row0 partials)
// Blocks [0,1024): windowed attn: 4 waves/block, 64 rows, KVBLK=64, K+V dbuf LDS,
//   preswizzled source + XOR reads, setprio, defer-max fast softmax (T13).
// Blocks [1024,1280): global-row-0 partials.
__global__ __launch_bounds__(256) void attn_win(
    const unsigned short* __restrict__ Qb,
    const unsigned short* __restrict__ Kb,
    const unsigned short* __restrict__ Vt,
    unsigned short* __restrict__ Ob,
    float* __restrict__ mw, float* __restrict__ lw, float* __restrict__ ow) {
  const int tid  = threadIdx.x;
  const int lane = tid & 63;
  const int wave = tid >> 6;

  if (blockIdx.x >= 1024) {  // ---------------- row0 partial path
    const int bid = blockIdx.x - 1024;
    const int c = bid & 15, h = bid >> 4;
    const int k = c * 256 + tid;
    __shared__ float qsh[HD];
    __shared__ float ps[256];
    __shared__ float redm[4], redl[4];
    __shared__ float red2[4][HD];
    const float LOG2E = 1.44269504f;

    if (tid < HD) qsh[tid] = bf2f(Qb[h * HD + tid]);
    __syncthreads();

    const unsigned short* kr = Kb + (size_t)k * HID + h * HD;
    float acc = 0.f;
#pragma unroll
    for (int v8 = 0; v8 < 8; v8++) {
      u16x8 kv = *reinterpret_cast<const u16x8*>(kr + v8 * 8);
#pragma unroll
      for (int j = 0; j < 8; j++) acc += qsh[v8 * 8 + j] * bf2f(kv[j]);
    }
    float s = acc * 0.125f;

    float m = s;
#pragma unroll
    for (int d = 1; d < 64; d <<= 1) m = fmaxf(m, __shfl_xor(m, d, 64));
    if (lane == 0) redm[wave] = m;
    __syncthreads();
    float m_c = fmaxf(fmaxf(redm[0], redm[1]), fmaxf(redm[2], redm[3]));

    float p = exp2f((s - m_c) * LOG2E);
    ps[tid] = p;
    float l = p;
#pragma unroll
    for (int d = 1; d < 64; d <<= 1) l += __shfl_xor(l, d, 64);
    if (lane == 0) redl[wave] = l;
    __syncthreads();
    float l_c = redl[0] + redl[1] + redl[2] + redl[3];

    const int d = tid & 63, grp = tid >> 6;
    const unsigned short* vrow = Vt + (size_t)(h * HD + d) * S_LEN + c * 256 + grp * 64;
    float a2 = 0.f;
#pragma unroll
    for (int v8 = 0; v8 < 8; v8++) {
      u16x8 vv = *reinterpret_cast<const u16x8*>(vrow + v8 * 8);
#pragma unroll
      for (int j = 0; j < 8; j++) a2 += ps[grp * 64 + v8 * 8 + j] * bf2f(vv[j]);
    }
    red2[grp][d] = a2;
    __syncthreads();
    if (tid < HD) {
      float o = red2[0][tid] + red2[1][tid] + red2[2][tid] + red2[3][tid];
      ow[(size_t)(h * 16 + c) * HD + tid] = o;
    }
    if (tid == 0) { mw[h * 16 + c] = m_c; lw[h * 16 + c] = l_c; }
    return;
  }

  // ---------------- windowed path
  __shared__ __align__(16) unsigned short Kl[2][64 * 64];  // 16 KB
  __shared__ __align__(16) unsigned short Vl[2][64 * 64];  // 16 KB (Vl[d][klocal])
  __shared__ __align__(16) unsigned short Ps[4][16 * 64];  // 8 KB
  const int L  = (blockIdx.x & 7) * 128 + (blockIdx.x >> 3);
  const int h  = L >> 6;
  const int q0 = (L & 63) * 64;
  const int qr   = q0 + wave * 16;
  const int cl = lane & 15, g = lane >> 4, rl = g * 4;
  const float SCL = 0.125f * 1.44269504f;  // scale * log2(e): exp2 domain

  int kw0 = q0 - 128; if (kw0 < 0) kw0 = 0;
  int kw1 = q0 + 192; if (kw1 > S_LEN) kw1 = S_LEN;
  const int nc = (kw1 - kw0) >> 6;                // 3 / 4 / 5 chunks

  const int s0 = tid, s1 = tid + 256;
  const int kr0 = s0 >> 3, kc0 = ((s0 & 7) ^ (kr0 & 7)) << 3;
  const int kr1 = s1 >> 3, kc1 = ((s1 & 7) ^ (kr1 & 7)) << 3;
  const unsigned short* Kbase = Kb + h * HD;
  const unsigned short* Vbase = Vt + (size_t)h * HD * S_LEN;

  auto stage = [&](int kb, int b) {
    gld_lds16(Kbase + (size_t)(kb + kr0) * HID + kc0, &Kl[b][s0 * 8]);
    gld_lds16(Kbase + (size_t)(kb + kr1) * HID + kc1, &Kl[b][s1 * 8]);
    gld_lds16(Vbase + (size_t)kr0 * S_LEN + kb + kc0, &Vl[b][s0 * 8]);
    gld_lds16(Vbase + (size_t)kr1 * S_LEN + kb + kc1, &Vl[b][s1 * 8]);
  };

  stage(kw0, 0);

  bf16x8 qf[2], k0f[2];
  {
    const unsigned short* qb = Qb + (size_t)(qr + cl) * HID + h * HD + g * 8;
    qf[0] = *reinterpret_cast<const bf16x8*>(qb);
    qf[1] = *reinterpret_cast<const bf16x8*>(qb + 32);
    const unsigned short* k0 = Kb + h * HD + g * 8;
    k0f[0] = *reinterpret_cast<const bf16x8*>(k0);
    k0f[1] = *reinterpret_cast<const bf16x8*>(k0 + 32);
  }
  float v0[4];
#pragma unroll
  for (int nt = 0; nt < 4; nt++)
    v0[nt] = bf2f(Vt[(size_t)(h * HD + nt * 16 + cl) * S_LEN]);

  float m_i[4] = {-1e30f, -1e30f, -1e30f, -1e30f};
  float l_i[4] = {0.f, 0.f, 0.f, 0.f};
  f32x4 oacc[4];
#pragma unroll
  for (int nt = 0; nt < 4; nt++) oacc[nt] = f32x4{0.f, 0.f, 0.f, 0.f};

  __syncthreads();  // chunk 0 landed

  for (int c = 0; c < nc; c++) {
    const int cur = c & 1;
    const int kb = kw0 + c * 64;
    if (c + 1 < nc) stage(kw0 + (c + 1) * 64, cur ^ 1);

    bf16x8 kf[4][2];
#pragma unroll
    for (int t = 0; t < 4; t++) {
      int R = t * 16 + cl;
      kf[t][0] = *reinterpret_cast<const bf16x8*>(&Kl[cur][R * 64 + ((g ^ (R & 7)) << 3)]);
      kf[t][1] = *reinterpret_cast<const bf16x8*>(&Kl[cur][R * 64 + (((g + 4) ^ (R & 7)) << 3)]);
    }
    f32x4 s4[4];
    __builtin_amdgcn_s_setprio(1);
#pragma unroll
    for (int t = 0; t < 4; t++) {
      s4[t] = f32x4{0.f, 0.f, 0.f, 0.f};
      s4[t] = __builtin_amdgcn_mfma_f32_16x16x32_bf16(qf[0], kf[t][0], s4[t], 0, 0, 0);
      s4[t] = __builtin_amdgcn_mfma_f32_16x16x32_bf16(qf[1], kf[t][1], s4[t], 0, 0, 0);
    }
    __builtin_amdgcn_s_setprio(0);

    float sv[4][4], tm[4];
    if (kb >= qr - 113 && kb <= qr + 65) {
#pragma unroll
      for (int i = 0; i < 4; i++) {
        tm[i] = -1e30f;
#pragma unroll
        for (int t = 0; t < 4; t++) {
          float v = s4[t][i] * SCL;
          sv[t][i] = v;
          tm[i] = fmaxf(tm[i], v);
        }
      }
    } else {
#pragma unroll
      for (int i = 0; i < 4; i++) {
        int row = qr + rl + i;
        tm[i] = -1e30f;
#pragma unroll
        for (int t = 0; t < 4; t++) {
          int col = kb + t * 16 + cl;
          int d = row - col;
          float v = (d <= HWIN && d >= -HWIN) ? s4[t][i] * SCL : -1e30f;
          sv[t][i] = v;
          tm[i] = fmaxf(tm[i], v);
        }
      }
    }

    // ---- defer-max (T13): if no value exceeds m_i + 8, skip max-reduce/rescale
    bool ok = true;
#pragma unroll
    for (int i = 0; i < 4; i++) ok = ok && (tm[i] <= m_i[i] + 8.0f);
    float p[4][4], ps[4];
    if (__all((int)ok)) {
#pragma unroll
      for (int i = 0; i < 4; i++) {
        float sum = 0.f;
#pragma unroll
        for (int t = 0; t < 4; t++) { p[t][i] = exp2f(sv[t][i] - m_i[i]); sum += p[t][i]; }
        ps[i] = sum;
      }
    } else {
#pragma unroll
      for (int dd = 1; dd < 16; dd <<= 1)
#pragma unroll
        for (int i = 0; i < 4; i++) tm[i] = fmaxf(tm[i], __shfl_xor(tm[i], dd, 16));
#pragma unroll
      for (int i = 0; i < 4; i++) {
        float mnew = fmaxf(m_i[i], tm[i]);
        float fac  = exp2f(m_i[i] - mnew);
        m_i[i] = mnew;
        float sum = 0.f;
#pragma unroll
        for (int t = 0; t < 4; t++) { p[t][i] = exp2f(sv[t][i] - mnew); sum += p[t][i]; }
        ps[i] = sum;
        l_i[i] *= fac;
#pragma unroll
        for (int nt = 0; nt < 4; nt++) oacc[nt][i] *= fac;
      }
    }
#pragma unroll
    for (int dd = 1; dd < 16; dd <<= 1)
#pragma unroll
      for (int i = 0; i < 4; i++) ps[i] += __shfl_xor(ps[i], dd, 16);
#pragma unroll
    for (int i = 0; i < 4; i++) l_i[i] += ps[i];

#pragma unroll
    for (int t = 0; t < 4; t++)
#pragma unroll
      for (int i = 0; i < 4; i++) {
        int row = rl + i;
        Ps[wave][row * 64 + ((t * 16 + cl) ^ ((row & 7) << 3))] = f2bf(p[t][i]);
      }
    bf16x8 pf[2];
    pf[0] = *reinterpret_cast<const bf16x8*>(&Ps[wave][cl * 64 + ((g * 8) ^ ((cl & 7) << 3))]);
    pf[1] = *reinterpret_cast<const bf16x8*>(&Ps[wave][cl * 64 + ((32 + g * 8) ^ ((cl & 7) << 3))]);

    __builtin_amdgcn_s_setprio(1);
#pragma unroll
    for (int nt = 0; nt < 4; nt++) {
      int row = nt * 16 + cl;
      bf16x8 vf0 = *reinterpret_cast<const bf16x8*>(&Vl[cur][row * 64 + ((g ^ (row & 7)) << 3)]);
      bf16x8 vf1 = *reinterpret_cast<const bf16x8*>(&Vl[cur][row * 64 + (((g + 4) ^ (row & 7)) << 3)]);
      oacc[nt] = __builtin_amdgcn_mfma_f32_16x16x32_bf16(pf[0], vf0, oacc[nt], 0, 0, 0);
      oacc[nt] = __builtin_amdgcn_mfma_f32_16x16x32_bf16(pf[1], vf1, oacc[nt], 0, 0, 0);
    }
    __builtin_amdgcn_s_setprio(0);

    __syncthreads();
  }

  // global key 0 epilogue (rows > 128 only)
  float part = 0.f;
#pragma unroll
  for (int s = 0; s < 2; s++)
#pragma unroll
    for (int j = 0; j < 8; j++) part += (float)qf[s][j] * (float)k0f[s][j];
  part += __shfl_xor(part, 16);
  part += __shfl_xor(part, 32);
  float s0q = part * SCL;
#pragma unroll
  for (int i = 0; i < 4; i++) {
    float z0 = __shfl(s0q, rl + i, 16);
    int row = qr + rl + i;
    if (row > HWIN) {
      float mnew = fmaxf(m_i[i], z0);
      float fac  = exp2f(m_i[i] - mnew);
      float p0   = exp2f(z0 - mnew);
      l_i[i] = l_i[i] * fac + p0;
#pragma unroll
      for (int nt = 0; nt < 4; nt++)
        oacc[nt][i] = oacc[nt][i] * fac + p0 * v0[nt];
    }
  }

#pragma unroll
  for (int nt = 0; nt < 4; nt++)
#pragma unroll
    for (int i = 0; i < 4; i++)
      Ob[(size_t)(qr + rl + i) * HID + h * HD + nt * 16 + cl] = f2bf(oacc[nt][i] / l_i[i]);
}

// ---------------------------------------------------------------- launch
extern "C" void kernel_launch(void* const* d_in, const int* in_sizes, int n_in,
                              void* d_out, int out_size, void* d_ws, size_t ws_size,
                              hipStream_t stream) {
  const float* x  = (const float*)d_in[0];
  const float* wq = (const float*)d_in[1];
  const float* wk = (const float*)d_in[2];
  const float* wv = (const float*)d_in[3];
  const float* wo = (const float*)d_in[4];
  float* out = (float*)d_out;
  char* ws = (char*)d_ws;
  const size_t MB = 1024ull * 1024ull;
  unsigned short* xb  = (unsigned short*)(ws + 0 * MB);
  unsigned short* wqb = (unsigned short*)(ws + 8 * MB);
  unsigned short* wkb = (unsigned short*)(ws + 10 * MB);
  unsigned short* wvb = (unsigned short*)(ws + 12 * MB);
  unsigned short* wob = (unsigned short*)(ws + 14 * MB);
  unsigned short* Qb  = (unsigned short*)(ws + 16 * MB);
  unsigned short* Kb  = (unsigned short*)(ws + 24 * MB);
  unsigned short* Vt  = (unsigned short*)(ws + 32 * MB);
  unsigned short* Ob  = (unsigned short*)(ws + 40 * MB);
  float* mw = (float*)(ws + 48 * MB);
  float* lw = (float*)(ws + 48 * MB + 4096);
  float* ow = (float*)(ws + 48 * MB + 8192);

  dim3 blk(256);
  convert_all<<<dim3(2048), blk, 0, stream>>>(
      x, wq, wk, wv, wo, xb, wqb, wkb, wvb, wob);
  gemm_qkv<<<dim3(S_LEN / 128, HID / 64, 3), blk, 0, stream>>>(
      xb, wqb, wkb, wvb, Qb, Kb, Vt);
  attn_win<<<dim3(1280), blk, 0, stream>>>(Qb, Kb, Vt, Ob, mw, lw, ow);
  gemm_proj<<<dim3(S_LEN / 128, HID / 64), blk, 0, stream>>>(
      Ob, wob, mw, lw, ow, out);
}

// Round 15
// 87.344 us; speedup vs baseline: 1.0678x; 1.0678x over previous
//
#include <hip/hip_runtime.h>
#include <hip/hip_bf16.h>
#include <stdint.h>

#define S_LEN 4096
#define HID   1024
#define NH    16
#define HD    64
#define HWIN  128

typedef __bf16 bf16x8 __attribute__((ext_vector_type(8)));
typedef float  f32x4  __attribute__((ext_vector_type(4)));
typedef unsigned short u16x8 __attribute__((ext_vector_type(8)));

typedef const __attribute__((address_space(1))) unsigned int* gas_ptr;
typedef __attribute__((address_space(3))) unsigned int* las_ptr;

__device__ __forceinline__ float bf2f(unsigned short u) {
  union { float f; uint32_t i; } w; w.i = ((uint32_t)u) << 16; return w.f;
}
__device__ __forceinline__ unsigned short f2bf(float f) {
  union { float f; uint32_t i; } w; w.f = f;
  uint32_t r = (w.i + 0x7FFFu + ((w.i >> 16) & 1u)) >> 16;
  return (unsigned short)r;
}

__device__ __forceinline__ void gld_lds16(const void* g, void* l) {
  __builtin_amdgcn_global_load_lds((gas_ptr)g, (las_ptr)l, 16, 0, 0);
}

// ---------------------------------------------------------------- convert (grid-stride)
__global__ __launch_bounds__(256) void convert_all(
    const float* __restrict__ x,
    const float* __restrict__ wq, const float* __restrict__ wk,
    const float* __restrict__ wv, const float* __restrict__ wo,
    unsigned short* __restrict__ xb,
    unsigned short* __restrict__ wqb, unsigned short* __restrict__ wkb,
    unsigned short* __restrict__ wvb, unsigned short* __restrict__ wob) {
  const int XF4 = (S_LEN * HID) / 4;      // 1048576
  const int WF4 = (HID * HID) / 4;        // 262144
  int i = blockIdx.x * 256 + threadIdx.x; // grid 2048 blocks -> 524288 threads
#pragma unroll
  for (int it = 0; it < 4; it++, i += 524288) {
    const float* in; unsigned short* out; int off;
    if (i < XF4) { in = x; out = xb; off = i; }
    else {
      int j = i - XF4;
      int w = j >> 18;
      off = j & (WF4 - 1);
      switch (w) {
        case 0:  in = wq; out = wqb; break;
        case 1:  in = wk; out = wkb; break;
        case 2:  in = wv; out = wvb; break;
        default: in = wo; out = wob; break;
      }
    }
    float4 v = reinterpret_cast<const float4*>(in)[off];
    ushort4 o;
    o.x = f2bf(v.x); o.y = f2bf(v.y); o.z = f2bf(v.z); o.w = f2bf(v.w);
    reinterpret_cast<ushort4*>(out)[off] = o;
  }
}

// ---------------------------------------------------------------- QKV GEMM (R13 known-good 128x128)
// C[M,N] = A[M,K] * B[N,K]^T. BK=64 single-buffer, XOR-swizzled LDS.
// mode 0: bf16 C[r*HID+c]; mode 1: bf16 transposed C[c*S_LEN+r] via LDS-transpose.
__device__ __forceinline__ void gemm_body(const unsigned short* __restrict__ A,
                                          const unsigned short* __restrict__ B,
                                          unsigned short* __restrict__ Cb, int mode) {
  __shared__ __align__(16) unsigned short SM[2 * 128 * 64];  // 32 KB (As|Bs, reused as T)
  unsigned short* As = SM;
  unsigned short* Bs = SM + 128 * 64;
  constexpr int K = HID;
  const int tid  = threadIdx.x;
  const int lane = tid & 63;
  const int wave = tid >> 6;
  const int wm = wave >> 1, wn = wave & 1;
  const int m0 = blockIdx.x * 128;
  const int n0 = blockIdx.y * 128;
  const int cl = lane & 15, g = lane >> 4;

  f32x4 acc[4][4];
#pragma unroll
  for (int i = 0; i < 4; i++)
#pragma unroll
    for (int j = 0; j < 4; j++) acc[i][j] = f32x4{0.f, 0.f, 0.f, 0.f};

  const unsigned short* Ap[4];
  const unsigned short* Bp[4];
  int ldso[4];
#pragma unroll
  for (int u = 0; u < 4; u++) {
    int s = tid + u * 256;
    int row = s >> 3, c16 = s & 7;
    int sc = ((c16 ^ (row & 7)) << 3);
    Ap[u] = A + (size_t)(m0 + row) * K + sc;
    Bp[u] = B + (size_t)(n0 + row) * K + sc;
    ldso[u] = s * 8;
  }

  for (int k0 = 0; k0 < K; k0 += 64) {
#pragma unroll
    for (int u = 0; u < 4; u++) {
      gld_lds16(Ap[u] + k0, &As[ldso[u]]);
      gld_lds16(Bp[u] + k0, &Bs[ldso[u]]);
    }
    __syncthreads();
#pragma unroll
    for (int kk = 0; kk < 2; kk++) {
      bf16x8 a[4], b[4];
#pragma unroll
      for (int mi = 0; mi < 4; mi++) {
        int row = wm * 64 + mi * 16 + cl;
        int c16 = (kk * 4 + g) ^ (row & 7);
        a[mi] = *reinterpret_cast<const bf16x8*>(&As[row * 64 + c16 * 8]);
      }
#pragma unroll
      for (int ni = 0; ni < 4; ni++) {
        int row = wn * 64 + ni * 16 + cl;
        int c16 = (kk * 4 + g) ^ (row & 7);
        b[ni] = *reinterpret_cast<const bf16x8*>(&Bs[row * 64 + c16 * 8]);
      }
#pragma unroll
      for (int mi = 0; mi < 4; mi++)
#pragma unroll
        for (int ni = 0; ni < 4; ni++)
          acc[mi][ni] = __builtin_amdgcn_mfma_f32_16x16x32_bf16(a[mi], b[ni], acc[mi][ni], 0, 0, 0);
    }
    __syncthreads();
  }

  const int rl = g * 4;
  if (mode == 1) {
#pragma unroll
    for (int mi = 0; mi < 4; mi++)
#pragma unroll
      for (int ni = 0; ni < 4; ni++) {
        int c = wn * 64 + ni * 16 + cl;
        int slot = (wm * 16 + mi * 4 + g) ^ ((c & 7) << 2);
        uint2 u;
        u.x = (uint32_t)f2bf(acc[mi][ni][0]) | ((uint32_t)f2bf(acc[mi][ni][1]) << 16);
        u.y = (uint32_t)f2bf(acc[mi][ni][2]) | ((uint32_t)f2bf(acc[mi][ni][3]) << 16);
        *reinterpret_cast<uint2*>(&SM[c * 128 + slot * 4]) = u;
      }
    __syncthreads();
    const int rgrp = tid & 15;
#pragma unroll
    for (int p = 0; p < 8; p++) {
      int c = p * 16 + (tid >> 4);
      int sa = (2 * rgrp) ^ ((c & 7) << 2);
      int sb = (2 * rgrp + 1) ^ ((c & 7) << 2);
      uint2 a2 = *reinterpret_cast<const uint2*>(&SM[c * 128 + sa * 4]);
      uint2 b2 = *reinterpret_cast<const uint2*>(&SM[c * 128 + sb * 4]);
      uint4 o{a2.x, a2.y, b2.x, b2.y};
      *reinterpret_cast<uint4*>(&Cb[(size_t)(n0 + c) * S_LEN + m0 + rgrp * 8]) = o;
    }
    return;
  }
#pragma unroll
  for (int mi = 0; mi < 4; mi++)
#pragma unroll
    for (int ni = 0; ni < 4; ni++)
#pragma unroll
      for (int i = 0; i < 4; i++) {
        int r = m0 + wm * 64 + mi * 16 + rl + i;
        int c = n0 + wn * 64 + ni * 16 + cl;
        Cb[(size_t)r * HID + c] = f2bf(acc[mi][ni][i]);
      }
}

__global__ __launch_bounds__(256, 2) void gemm_qkv(
    const unsigned short* __restrict__ xb,
    const unsigned short* __restrict__ wqb, const unsigned short* __restrict__ wkb,
    const unsigned short* __restrict__ wvb,
    unsigned short* __restrict__ Qb, unsigned short* __restrict__ Kb,
    unsigned short* __restrict__ Vt) {
  const unsigned short* B = (blockIdx.z == 0) ? wqb : (blockIdx.z == 1) ? wkb : wvb;
  unsigned short* C       = (blockIdx.z == 0) ? Qb  : (blockIdx.z == 1) ? Kb  : Vt;
  int mode = (blockIdx.z == 2) ? 1 : 0;
  gemm_body(xb, B, C, mode);
}

// ---------------------------------------------------------------- proj GEMM: BM=128, BN=64 (R13 known-good)
__global__ __launch_bounds__(256, 2) void gemm_proj(
    unsigned short* __restrict__ Ob, const unsigned short* __restrict__ wob,
    const float* __restrict__ mw, const float* __restrict__ lw,
    const float* __restrict__ ow, float* __restrict__ out) {
  if (blockIdx.x == 0) {
    const float LOG2E = 1.44269504f;
    for (int cc = threadIdx.x; cc < HID; cc += 256) {
      int h = cc >> 6, d = cc & 63;
      float m_g = -1e30f;
#pragma unroll
      for (int c = 0; c < 16; c++) m_g = fmaxf(m_g, mw[h * 16 + c]);
      float lsum = 0.f, osum = 0.f;
#pragma unroll
      for (int c = 0; c < 16; c++) {
        float w = exp2f((mw[h * 16 + c] - m_g) * LOG2E);
        lsum += lw[h * 16 + c] * w;
        osum += ow[(size_t)(h * 16 + c) * HD + d] * w;
      }
      Ob[cc] = f2bf(osum / lsum);
    }
    asm volatile("s_waitcnt vmcnt(0)" ::: "memory");
    __syncthreads();
  }

  __shared__ __align__(16) unsigned short As[128 * 64];  // 16 KB
  __shared__ __align__(16) unsigned short Bs[64 * 64];   // 8 KB
  constexpr int K = HID;
  const int tid  = threadIdx.x;
  const int lane = tid & 63;
  const int wave = tid >> 6;
  const int wm = wave >> 1, wn = wave & 1;
  const int m0 = blockIdx.x * 128;
  const int n0 = blockIdx.y * 64;
  const int cl = lane & 15, g = lane >> 4;

  f32x4 acc[4][2];
#pragma unroll
  for (int i = 0; i < 4; i++)
#pragma unroll
    for (int j = 0; j < 2; j++) acc[i][j] = f32x4{0.f, 0.f, 0.f, 0.f};

  const unsigned short* Ap[4];
  const unsigned short* Bp[2];
  int ldsoA[4], ldsoB[2];
#pragma unroll
  for (int u = 0; u < 4; u++) {
    int s = tid + u * 256;
    int row = s >> 3, c16 = s & 7;
    Ap[u] = Ob + (size_t)(m0 + row) * K + ((c16 ^ (row & 7)) << 3);
    ldsoA[u] = s * 8;
  }
#pragma unroll
  for (int u = 0; u < 2; u++) {
    int s = tid + u * 256;
    int row = s >> 3, c16 = s & 7;
    Bp[u] = wob + (size_t)(n0 + row) * K + ((c16 ^ (row & 7)) << 3);
    ldsoB[u] = s * 8;
  }

  for (int k0 = 0; k0 < K; k0 += 64) {
#pragma unroll
    for (int u = 0; u < 4; u++) gld_lds16(Ap[u] + k0, &As[ldsoA[u]]);
#pragma unroll
    for (int u = 0; u < 2; u++) gld_lds16(Bp[u] + k0, &Bs[ldsoB[u]]);
    __syncthreads();
#pragma unroll
    for (int kk = 0; kk < 2; kk++) {
      bf16x8 a[4], b[2];
#pragma unroll
      for (int mi = 0; mi < 4; mi++) {
        int row = wm * 64 + mi * 16 + cl;
        int c16 = (kk * 4 + g) ^ (row & 7);
        a[mi] = *reinterpret_cast<const bf16x8*>(&As[row * 64 + c16 * 8]);
      }
#pragma unroll
      for (int ni = 0; ni < 2; ni++) {
        int row = wn * 32 + ni * 16 + cl;
        int c16 = (kk * 4 + g) ^ (row & 7);
        b[ni] = *reinterpret_cast<const bf16x8*>(&Bs[row * 64 + c16 * 8]);
      }
#pragma unroll
      for (int mi = 0; mi < 4; mi++)
#pragma unroll
        for (int ni = 0; ni < 2; ni++)
          acc[mi][ni] = __builtin_amdgcn_mfma_f32_16x16x32_bf16(a[mi], b[ni], acc[mi][ni], 0, 0, 0);
    }
    __syncthreads();
  }

  const int rl = g * 4;
#pragma unroll
  for (int mi = 0; mi < 4; mi++)
#pragma unroll
    for (int ni = 0; ni < 2; ni++)
#pragma unroll
      for (int i = 0; i < 4; i++) {
        int r = m0 + wm * 64 + mi * 16 + rl + i;
        int c = n0 + wn * 32 + ni * 16 + cl;
        out[(size_t)r * HID + c] = acc[mi][ni][i];
      }
}

// ---------------------------------------------------------------- windowed attention (+ fused row0 partials)
// Blocks [0,1024): windowed attn: 4 waves/block, 64 rows, KVBLK=64, K+V dbuf LDS,
//   preswizzled source + XOR reads, setprio, defer-max (T13).
// Blocks [1024,1280): global-row-0 partials.
__global__ __launch_bounds__(256) void attn_win(
    const unsigned short* __restrict__ Qb,
    const unsigned short* __restrict__ Kb,
    const unsigned short* __restrict__ Vt,
    unsigned short* __restrict__ Ob,
    float* __restrict__ mw, float* __restrict__ lw, float* __restrict__ ow) {
  const int tid  = threadIdx.x;
  const int lane = tid & 63;
  const int wave = tid >> 6;

  if (blockIdx.x >= 1024) {  // ---------------- row0 partial path
    const int bid = blockIdx.x - 1024;
    const int c = bid & 15, h = bid >> 4;
    const int k = c * 256 + tid;
    __shared__ float qsh[HD];
    __shared__ float ps[256];
    __shared__ float redm[4], redl[4];
    __shared__ float red2[4][HD];
    const float LOG2E = 1.44269504f;

    if (tid < HD) qsh[tid] = bf2f(Qb[h * HD + tid]);
    __syncthreads();

    const unsigned short* kr = Kb + (size_t)k * HID + h * HD;
    float acc = 0.f;
#pragma unroll
    for (int v8 = 0; v8 < 8; v8++) {
      u16x8 kv = *reinterpret_cast<const u16x8*>(kr + v8 * 8);
#pragma unroll
      for (int j = 0; j < 8; j++) acc += qsh[v8 * 8 + j] * bf2f(kv[j]);
    }
    float s = acc * 0.125f;

    float m = s;
#pragma unroll
    for (int d = 1; d < 64; d <<= 1) m = fmaxf(m, __shfl_xor(m, d, 64));
    if (lane == 0) redm[wave] = m;
    __syncthreads();
    float m_c = fmaxf(fmaxf(redm[0], redm[1]), fmaxf(redm[2], redm[3]));

    float p = exp2f((s - m_c) * LOG2E);
    ps[tid] = p;
    float l = p;
#pragma unroll
    for (int d = 1; d < 64; d <<= 1) l += __shfl_xor(l, d, 64);
    if (lane == 0) redl[wave] = l;
    __syncthreads();
    float l_c = redl[0] + redl[1] + redl[2] + redl[3];

    const int d = tid & 63, grp = tid >> 6;
    const unsigned short* vrow = Vt + (size_t)(h * HD + d) * S_LEN + c * 256 + grp * 64;
    float a2 = 0.f;
#pragma unroll
    for (int v8 = 0; v8 < 8; v8++) {
      u16x8 vv = *reinterpret_cast<const u16x8*>(vrow + v8 * 8);
#pragma unroll
      for (int j = 0; j < 8; j++) a2 += ps[grp * 64 + v8 * 8 + j] * bf2f(vv[j]);
    }
    red2[grp][d] = a2;
    __syncthreads();
    if (tid < HD) {
      float o = red2[0][tid] + red2[1][tid] + red2[2][tid] + red2[3][tid];
      ow[(size_t)(h * 16 + c) * HD + tid] = o;
    }
    if (tid == 0) { mw[h * 16 + c] = m_c; lw[h * 16 + c] = l_c; }
    return;
  }

  // ---------------- windowed path
  __shared__ __align__(16) unsigned short Kl[2][64 * 64];  // 16 KB
  __shared__ __align__(16) unsigned short Vl[2][64 * 64];  // 16 KB (Vl[d][klocal])
  __shared__ __align__(16) unsigned short Ps[4][16 * 64];  // 8 KB
  const int L  = (blockIdx.x & 7) * 128 + (blockIdx.x >> 3);
  const int h  = L >> 6;
  const int q0 = (L & 63) * 64;
  const int qr   = q0 + wave * 16;
  const int cl = lane & 15, g = lane >> 4, rl = g * 4;
  const float SCL = 0.125f * 1.44269504f;  // scale * log2(e): exp2 domain

  int kw0 = q0 - 128; if (kw0 < 0) kw0 = 0;
  int kw1 = q0 + 192; if (kw1 > S_LEN) kw1 = S_LEN;
  const int nc = (kw1 - kw0) >> 6;                // 3 / 4 / 5 chunks

  const int s0 = tid, s1 = tid + 256;
  const int kr0 = s0 >> 3, kc0 = ((s0 & 7) ^ (kr0 & 7)) << 3;
  const int kr1 = s1 >> 3, kc1 = ((s1 & 7) ^ (kr1 & 7)) << 3;
  const unsigned short* Kbase = Kb + h * HD;
  const unsigned short* Vbase = Vt + (size_t)h * HD * S_LEN;

  auto stage = [&](int kb, int b) {
    gld_lds16(Kbase + (size_t)(kb + kr0) * HID + kc0, &Kl[b][s0 * 8]);
    gld_lds16(Kbase + (size_t)(kb + kr1) * HID + kc1, &Kl[b][s1 * 8]);
    gld_lds16(Vbase + (size_t)kr0 * S_LEN + kb + kc0, &Vl[b][s0 * 8]);
    gld_lds16(Vbase + (size_t)kr1 * S_LEN + kb + kc1, &Vl[b][s1 * 8]);
  };

  stage(kw0, 0);

  bf16x8 qf[2], k0f[2];
  {
    const unsigned short* qb = Qb + (size_t)(qr + cl) * HID + h * HD + g * 8;
    qf[0] = *reinterpret_cast<const bf16x8*>(qb);
    qf[1] = *reinterpret_cast<const bf16x8*>(qb + 32);
    const unsigned short* k0 = Kb + h * HD + g * 8;
    k0f[0] = *reinterpret_cast<const bf16x8*>(k0);
    k0f[1] = *reinterpret_cast<const bf16x8*>(k0 + 32);
  }
  float v0[4];
#pragma unroll
  for (int nt = 0; nt < 4; nt++)
    v0[nt] = bf2f(Vt[(size_t)(h * HD + nt * 16 + cl) * S_LEN]);

  float m_i[4] = {-1e30f, -1e30f, -1e30f, -1e30f};
  float l_i[4] = {0.f, 0.f, 0.f, 0.f};
  f32x4 oacc[4];
#pragma unroll
  for (int nt = 0; nt < 4; nt++) oacc[nt] = f32x4{0.f, 0.f, 0.f, 0.f};

  __syncthreads();  // chunk 0 landed

  for (int c = 0; c < nc; c++) {
    const int cur = c & 1;
    const int kb = kw0 + c * 64;
    if (c + 1 < nc) stage(kw0 + (c + 1) * 64, cur ^ 1);

    bf16x8 kf[4][2];
#pragma unroll
    for (int t = 0; t < 4; t++) {
      int R = t * 16 + cl;
      kf[t][0] = *reinterpret_cast<const bf16x8*>(&Kl[cur][R * 64 + ((g ^ (R & 7)) << 3)]);
      kf[t][1] = *reinterpret_cast<const bf16x8*>(&Kl[cur][R * 64 + (((g + 4) ^ (R & 7)) << 3)]);
    }
    f32x4 s4[4];
    __builtin_amdgcn_s_setprio(1);
#pragma unroll
    for (int t = 0; t < 4; t++) {
      s4[t] = f32x4{0.f, 0.f, 0.f, 0.f};
      s4[t] = __builtin_amdgcn_mfma_f32_16x16x32_bf16(qf[0], kf[t][0], s4[t], 0, 0, 0);
      s4[t] = __builtin_amdgcn_mfma_f32_16x16x32_bf16(qf[1], kf[t][1], s4[t], 0, 0, 0);
    }
    __builtin_amdgcn_s_setprio(0);

    float sv[4][4], tm[4];
    if (kb >= qr - 113 && kb <= qr + 65) {
#pragma unroll
      for (int i = 0; i < 4; i++) {
        tm[i] = -1e30f;
#pragma unroll
        for (int t = 0; t < 4; t++) {
          float v = s4[t][i] * SCL;
          sv[t][i] = v;
          tm[i] = fmaxf(tm[i], v);
        }
      }
    } else {
#pragma unroll
      for (int i = 0; i < 4; i++) {
        int row = qr + rl + i;
        tm[i] = -1e30f;
#pragma unroll
        for (int t = 0; t < 4; t++) {
          int col = kb + t * 16 + cl;
          int d = row - col;
          float v = (d <= HWIN && d >= -HWIN) ? s4[t][i] * SCL : -1e30f;
          sv[t][i] = v;
          tm[i] = fmaxf(tm[i], v);
        }
      }
    }

    // ---- defer-max (T13): if no value exceeds m_i + 8, skip max-reduce/rescale
    bool ok = true;
#pragma unroll
    for (int i = 0; i < 4; i++) ok = ok && (tm[i] <= m_i[i] + 8.0f);
    float p[4][4], ps[4];
    if (__all((int)ok)) {
#pragma unroll
      for (int i = 0; i < 4; i++) {
        float sum = 0.f;
#pragma unroll
        for (int t = 0; t < 4; t++) { p[t][i] = exp2f(sv[t][i] - m_i[i]); sum += p[t][i]; }
        ps[i] = sum;
      }
    } else {
#pragma unroll
      for (int dd = 1; dd < 16; dd <<= 1)
#pragma unroll
        for (int i = 0; i < 4; i++) tm[i] = fmaxf(tm[i], __shfl_xor(tm[i], dd, 16));
#pragma unroll
      for (int i = 0; i < 4; i++) {
        float mnew = fmaxf(m_i[i], tm[i]);
        float fac  = exp2f(m_i[i] - mnew);
        m_i[i] = mnew;
        float sum = 0.f;
#pragma unroll
        for (int t = 0; t < 4; t++) { p[t][i] = exp2f(sv[t][i] - mnew); sum += p[t][i]; }
        ps[i] = sum;
        l_i[i] *= fac;
#pragma unroll
        for (int nt = 0; nt < 4; nt++) oacc[nt][i] *= fac;
      }
    }
#pragma unroll
    for (int dd = 1; dd < 16; dd <<= 1)
#pragma unroll
      for (int i = 0; i < 4; i++) ps[i] += __shfl_xor(ps[i], dd, 16);
#pragma unroll
    for (int i = 0; i < 4; i++) l_i[i] += ps[i];

#pragma unroll
    for (int t = 0; t < 4; t++)
#pragma unroll
      for (int i = 0; i < 4; i++) {
        int row = rl + i;
        Ps[wave][row * 64 + ((t * 16 + cl) ^ ((row & 7) << 3))] = f2bf(p[t][i]);
      }
    bf16x8 pf[2];
    pf[0] = *reinterpret_cast<const bf16x8*>(&Ps[wave][cl * 64 + ((g * 8) ^ ((cl & 7) << 3))]);
    pf[1] = *reinterpret_cast<const bf16x8*>(&Ps[wave][cl * 64 + ((32 + g * 8) ^ ((cl & 7) << 3))]);

    __builtin_amdgcn_s_setprio(1);
#pragma unroll
    for (int nt = 0; nt < 4; nt++) {
      int row = nt * 16 + cl;
      bf16x8 vf0 = *reinterpret_cast<const bf16x8*>(&Vl[cur][row * 64 + ((g ^ (row & 7)) << 3)]);
      bf16x8 vf1 = *reinterpret_cast<const bf16x8*>(&Vl[cur][row * 64 + (((g + 4) ^ (row & 7)) << 3)]);
      oacc[nt] = __builtin_amdgcn_mfma_f32_16x16x32_bf16(pf[0], vf0, oacc[nt], 0, 0, 0);
      oacc[nt] = __builtin_amdgcn_mfma_f32_16x16x32_bf16(pf[1], vf1, oacc[nt], 0, 0, 0);
    }
    __builtin_amdgcn_s_setprio(0);

    __syncthreads();
  }

  // global key 0 epilogue (rows > 128 only)
  float part = 0.f;
#pragma unroll
  for (int s = 0; s < 2; s++)
#pragma unroll
    for (int j = 0; j < 8; j++) part += (float)qf[s][j] * (float)k0f[s][j];
  part += __shfl_xor(part, 16);
  part += __shfl_xor(part, 32);
  float s0q = part * SCL;
#pragma unroll
  for (int i = 0; i < 4; i++) {
    float z0 = __shfl(s0q, rl + i, 16);
    int row = qr + rl + i;
    if (row > HWIN) {
      float mnew = fmaxf(m_i[i], z0);
      float fac  = exp2f(m_i[i] - mnew);
      float p0   = exp2f(z0 - mnew);
      l_i[i] = l_i[i] * fac + p0;
#pragma unroll
      for (int nt = 0; nt < 4; nt++)
        oacc[nt][i] = oacc[nt][i] * fac + p0 * v0[nt];
    }
  }

#pragma unroll
  for (int nt = 0; nt < 4; nt++)
#pragma unroll
    for (int i = 0; i < 4; i++)
      Ob[(size_t)(qr + rl + i) * HID + h * HD + nt * 16 + cl] = f2bf(oacc[nt][i] / l_i[i]);
}

// ---------------------------------------------------------------- launch
extern "C" void kernel_launch(void* const* d_in, const int* in_sizes, int n_in,
                              void* d_out, int out_size, void* d_ws, size_t ws_size,
                              hipStream_t stream) {
  const float* x  = (const float*)d_in[0];
  const float* wq = (const float*)d_in[1];
  const float* wk = (const float*)d_in[2];
  const float* wv = (const float*)d_in[3];
  const float* wo = (const float*)d_in[4];
  float* out = (float*)d_out;
  char* ws = (char*)d_ws;
  const size_t MB = 1024ull * 1024ull;
  unsigned short* xb  = (unsigned short*)(ws + 0 * MB);
  unsigned short* wqb = (unsigned short*)(ws + 8 * MB);
  unsigned short* wkb = (unsigned short*)(ws + 10 * MB);
  unsigned short* wvb = (unsigned short*)(ws + 12 * MB);
  unsigned short* wob = (unsigned short*)(ws + 14 * MB);
  unsigned short* Qb  = (unsigned short*)(ws + 16 * MB);
  unsigned short* Kb  = (unsigned short*)(ws + 24 * MB);
  unsigned short* Vt  = (unsigned short*)(ws + 32 * MB);
  unsigned short* Ob  = (unsigned short*)(ws + 40 * MB);
  float* mw = (float*)(ws + 48 * MB);
  float* lw = (float*)(ws + 48 * MB + 4096);
  float* ow = (float*)(ws + 48 * MB + 8192);

  dim3 blk(256);
  convert_all<<<dim3(2048), blk, 0, stream>>>(
      x, wq, wk, wv, wo, xb, wqb, wkb, wvb, wob);
  gemm_qkv<<<dim3(S_LEN / 128, HID / 128, 3), blk, 0, stream>>>(
      xb, wqb, wkb, wvb, Qb, Kb, Vt);
  attn_win<<<dim3(1280), blk, 0, stream>>>(Qb, Kb, Vt, Ob, mw, lw, ow);
  gemm_proj<<<dim3(S_LEN / 128, HID / 64), blk, 0, stream>>>(
      Ob, wob, mw, lw, ow, out);
}